// Round 7
// baseline (373.516 us; speedup 1.0000x reference)
//
#include <hip/hip_runtime.h>
#include <math.h>

#define DIMC   1024
#define NHEADS 16
#define HDIM   64
#define BATCH  2
#define SEQ    2048

#define MTOT   (BATCH * SEQ)          // 4096 rows
#define QKVN   (3 * DIMC)             // 3072
#define QKVSZ  ((size_t)BATCH * NHEADS * SEQ * HDIM)  // 4194304 elems per tensor
#define HEADEL ((size_t)SEQ * HDIM)   // 131072 shorts per head

// SCALE * log2(e): folded into Q at the qkv epilogue so attention uses exp2.
#define QSCALE 0.18033688011112042f

typedef __attribute__((ext_vector_type(8))) short bf16x8;
typedef __attribute__((ext_vector_type(4))) short bf16x4;
typedef __attribute__((ext_vector_type(4))) float f32x4;

static __device__ inline short f2bf(float f) {
    union { float f; unsigned u; } v; v.f = f;
    unsigned r = v.u + 0x7fffu + ((v.u >> 16) & 1u);   // RNE
    return (short)(r >> 16);
}

// packed f32x2 -> bf16x2 (RNE), low16 = lo, high16 = hi. No builtin on gfx950.
static __device__ inline unsigned cvt_pk_bf16(float lo, float hi) {
    unsigned r;
    asm("v_cvt_pk_bf16_f32 %0, %1, %2" : "=v"(r) : "v"(lo), "v"(hi));
    return r;
}

#if __has_builtin(__builtin_amdgcn_exp2f)
#define EXP2F(x) __builtin_amdgcn_exp2f(x)
#else
#define EXP2F(x) exp2f(x)
#endif

// ---------------------------------------------------------------------------
// fused fp32 -> bf16 cast of x, w_qkv, w_proj (memory-bound, one launch)
// ---------------------------------------------------------------------------
#define NXB  (MTOT * DIMC / 2048)     // 2048 blocks
#define NWQB (QKVN * DIMC / 2048)     // 1536
#define NWPB (DIMC * DIMC / 2048)     // 512

__global__ __launch_bounds__(256) void cast_all(
    const float* __restrict__ x,  const float* __restrict__ wq,
    const float* __restrict__ wp, short* __restrict__ xb,
    short* __restrict__ wqb, short* __restrict__ wpb)
{
    const float* in; short* out; int base;
    int bid = blockIdx.x;
    if (bid < NXB)              { in = x;  out = xb;  base = bid; }
    else if (bid < NXB + NWQB)  { in = wq; out = wqb; base = bid - NXB; }
    else                        { in = wp; out = wpb; base = bid - NXB - NWQB; }
    int i = (base * 256 + threadIdx.x) * 8;
    float4 a = *(const float4*)&in[i];
    float4 b = *(const float4*)&in[i + 4];
    bf16x8 o;
    o[0] = f2bf(a.x); o[1] = f2bf(a.y); o[2] = f2bf(a.z); o[3] = f2bf(a.w);
    o[4] = f2bf(b.x); o[5] = f2bf(b.y); o[6] = f2bf(b.z); o[7] = f2bf(b.w);
    *(bf16x8*)&out[i] = o;
}

// ---------------------------------------------------------------------------
// async global->LDS, 16B per lane
// ---------------------------------------------------------------------------
__device__ __forceinline__ void gload16(const void* g, void* l) {
    __builtin_amdgcn_global_load_lds(
        (const __attribute__((address_space(1))) unsigned*)g,
        (__attribute__((address_space(3))) unsigned*)l, 16, 0, 0);
}

#define BAR() do { __builtin_amdgcn_s_barrier(); \
                   __builtin_amdgcn_sched_barrier(0); } while (0)
#define VWAIT8() asm volatile("s_waitcnt vmcnt(8)" ::: "memory")
#define VWAIT0() asm volatile("s_waitcnt vmcnt(0)" ::: "memory")

// ---------------------------------------------------------------------------
// Kernel 1: qkv GEMM, 256x256 tile, BK=64, 8 waves (2M x 4N).
// ROUND-5 STRUCTURE (reverted from round-6's 4-sub-phase pacing, which cost
// +8us: with 1 block/CU there is no co-resident block to fill the extra
// barrier drains -- pacing barriers are pure serialization here).
//
// Counted-vmcnt double-buffer: all 8 next-tile panel loads issued at the top
// of each K-iteration, then vmcnt(8) retires exactly the current tile's 8
// loads while the next tile's 8 stay in flight across the whole compute
// region. Tile-granular wait is required for correctness (per-phase waits
// race -- round-1 bug). Exactly 2 barriers/tile.
//
// Operand reuse: B fragments for BOTH N-halves loaded once per K-tile and
// held live (8 ds_read_b128); each A-half loaded once (8 reads) and feeds
// all 4 accumulator columns. 24 reads/wave/K-tile.
//
// Bank swizzle: LDS[r][g^(r&7)] = G[r][g] on 16B granules, applied on the
// global source (gload_lds dest stays linear) and on the ds_read address.
// ---------------------------------------------------------------------------
__device__ __forceinline__ void stage_panel(const short* __restrict__ src,
                                            int row0, int k0,
                                            short* dst, int tid)
{
#pragma unroll
    for (int u = 0; u < 2; ++u) {
        const int gidx = u * 512 + tid;        // 16B granule index in panel
        const int rl   = gidx >> 3;            // row in panel (0..127)
        const int cc   = gidx & 7;             // 16B col granule (0..7)
        gload16(&src[(size_t)(row0 + rl) * 1024 + k0 + ((cc ^ (rl & 7)) << 3)],
                &dst[(size_t)gidx << 3]);      // linear LDS dest
    }
}

__device__ __forceinline__ void load_b(const short* Bs, int wn, int nh,
                                       int lid, int quad, bf16x8 (&bfr)[2][2])
{
#pragma unroll
    for (int j2 = 0; j2 < 2; ++j2) {
        const int rb = wn + (nh * 2 + j2) * 16 + lid;
#pragma unroll
        for (int kk = 0; kk < 2; ++kk)
            bfr[j2][kk] = *(const bf16x8*)
                &Bs[rb * 64 + (((kk * 4 + quad) ^ (rb & 7)) << 3)];
    }
}

template<int MH>
__device__ __forceinline__ void half_compute(
    const short* As, int wm, int lid, int quad,
    const bf16x8 (&b0)[2][2], const bf16x8 (&b1)[2][2],
    f32x4 (&acc)[8][4])
{
    bf16x8 af[4][2];
#pragma unroll
    for (int i2 = 0; i2 < 4; ++i2) {
        const int r = wm + (MH * 4 + i2) * 16 + lid;
#pragma unroll
        for (int kk = 0; kk < 2; ++kk)
            af[i2][kk] = *(const bf16x8*)
                &As[r * 64 + (((kk * 4 + quad) ^ (r & 7)) << 3)];
    }
    __builtin_amdgcn_s_setprio(1);
#pragma unroll
    for (int i2 = 0; i2 < 4; ++i2)
#pragma unroll
        for (int kk = 0; kk < 2; ++kk) {
            acc[MH * 4 + i2][0] = __builtin_amdgcn_mfma_f32_16x16x32_bf16(
                af[i2][kk], b0[0][kk], acc[MH * 4 + i2][0], 0, 0, 0);
            acc[MH * 4 + i2][1] = __builtin_amdgcn_mfma_f32_16x16x32_bf16(
                af[i2][kk], b0[1][kk], acc[MH * 4 + i2][1], 0, 0, 0);
            acc[MH * 4 + i2][2] = __builtin_amdgcn_mfma_f32_16x16x32_bf16(
                af[i2][kk], b1[0][kk], acc[MH * 4 + i2][2], 0, 0, 0);
            acc[MH * 4 + i2][3] = __builtin_amdgcn_mfma_f32_16x16x32_bf16(
                af[i2][kk], b1[1][kk], acc[MH * 4 + i2][3], 0, 0, 0);
        }
    __builtin_amdgcn_s_setprio(0);
}

__global__ __launch_bounds__(512, 2) void qkv_mfma(
    const short* __restrict__ xb,    // [4096][1024] bf16
    const short* __restrict__ wb,    // [3072][1024] bf16
    const float* __restrict__ bias,  // [3072] fp32
    short* __restrict__ qkvb)        // Q|Kf|Vf bf16
{
    extern __shared__ short lds[];   // [2][A 256*64 | B 256*64] = 128 KiB

    const int tid = threadIdx.x;
    // bijective XCD-chunked swizzle: nwg=192, 192%8==0
    const int T  = (blockIdx.x & 7) * 24 + (blockIdx.x >> 3);
    const int m0 = (T / 12) * 256;
    const int j0 = (T % 12) * 256;

    const int lane = tid & 63;
    const int w    = tid >> 6;
    const int quad = lane >> 4;
    const int lid  = lane & 15;
    const int wm = (w >> 2) * 128;   // wave_m in {0,1}
    const int wn = (w & 3) * 64;     // wave_n in {0..3}

    f32x4 acc[8][4];
#pragma unroll
    for (int i = 0; i < 8; ++i)
#pragma unroll
        for (int j = 0; j < 4; ++j) acc[i][j] = (f32x4){0.f, 0.f, 0.f, 0.f};

    // prologue: stage K-tile 0 into buf0
    stage_panel(xb, m0,       0, lds,                 tid);
    stage_panel(xb, m0 + 128, 0, lds + 8192,          tid);
    stage_panel(wb, j0,       0, lds + 32768,         tid);
    stage_panel(wb, j0 + 128, 0, lds + 32768 + 8192,  tid);

#pragma unroll 2
    for (int kt = 0; kt < 15; ++kt) {
        const int cb = (kt & 1) << 14;
        const int nb = (~kt & 1) << 14;
        const int k1 = (kt + 1) << 6;
        const short* Ac = lds + cb;
        const short* Bc = lds + 32768 + cb;
        short* An = lds + nb;
        short* Bn = lds + 32768 + nb;

        // issue ALL next-tile panel loads up front (8 per thread)
        stage_panel(xb, m0,       k1, An,        tid);
        stage_panel(xb, m0 + 128, k1, An + 8192, tid);
        stage_panel(wb, j0,       k1, Bn,        tid);
        stage_panel(wb, j0 + 128, k1, Bn + 8192, tid);

        // retire current tile's 8 loads; keep next tile's 8 in flight
        VWAIT8(); BAR();
        {
            bf16x8 b0[2][2], b1[2][2];
            load_b(Bc, wn, 0, lid, quad, b0);
            load_b(Bc, wn, 1, lid, quad, b1);
            half_compute<0>(Ac, wm, lid, quad, b0, b1, acc);
            half_compute<1>(Ac, wm, lid, quad, b0, b1, acc);
        }
        BAR();                       // all waves done reading cb before it is
                                     // overwritten by next iteration's stage
    }
    // peeled last K-tile (kt=15, buf1, nothing left to stage)
    {
        const short* Ac = lds + 16384;
        const short* Bc = lds + 32768 + 16384;
        VWAIT0(); BAR();
        bf16x8 b0[2][2], b1[2][2];
        load_b(Bc, wn, 0, lid, quad, b0);
        load_b(Bc, wn, 1, lid, quad, b1);
        half_compute<0>(Ac, wm, lid, quad, b0, b1, acc);
        half_compute<1>(Ac, wm, lid, quad, b0, b1, acc);
    }

    // ---- epilogue ----
    const int s = j0 >> 10;            // uniform: 0:q 1:k 2:v

    if (s == 0) {
#pragma unroll
        for (int jb = 0; jb < 4; ++jb) {
            const int jj = j0 + wn + jb * 16 + lid;
            const int hh = (jj & 1023) >> 6;
            const int dd = jj & 63;
            const float bv = bias[jj];
#pragma unroll
            for (int i = 0; i < 8; ++i)
#pragma unroll
                for (int r = 0; r < 4; ++r) {
                    const int mrow = m0 + wm + i * 16 + quad * 4 + r;
                    const int b_ = mrow >> 11, nn = mrow & 2047;
                    qkvb[((size_t)(b_ * NHEADS + hh) * SEQ + nn) * HDIM + dd] =
                        f2bf((acc[i][jb][r] + bv) * QSCALE);
                }
        }
    } else if (s == 1) {
        // K: permuted fragment-major.
#pragma unroll
        for (int jb = 0; jb < 4; ++jb) {
            const int jj = j0 + wn + jb * 16 + lid;
            const int hh = (jj & 1023) >> 6;
            const int dd = jj & 63;
            const int c2 = dd >> 5;
            const int qd = (dd >> 3) & 3;
            const int jo = dd & 7;
            const float bv = bias[jj];
#pragma unroll
            for (int i = 0; i < 8; ++i) {
                const int mrow0 = m0 + wm + i * 16;
                const int b_ = mrow0 >> 11;
                const int n0 = mrow0 & 2047;
                const int t32 = n0 >> 5;
                const int i16 = (n0 >> 4) & 1;
                const int c = quad & 1;
                const int lidb = (i16 * 2 + (quad >> 1)) * 4;
                size_t base = QKVSZ + (size_t)(b_ * NHEADS + hh) * HEADEL +
                              (size_t)(t32 * 4 + c2 * 2 + c) * 512 +
                              (qd * 16 + lidb) * 8 + jo;
#pragma unroll
                for (int r = 0; r < 4; ++r)
                    qkvb[base + r * 8] = f2bf(acc[i][jb][r] + bv);
            }
        }
    } else {
        // V: x32-A fragment-major.
#pragma unroll
        for (int jb = 0; jb < 4; ++jb) {
            const int jj = j0 + wn + jb * 16 + lid;
            const int hh = (jj & 1023) >> 6;
            const int dd = jj & 63;
            const int fb = dd >> 4;
            const int dl = dd & 15;
            const float bv = bias[jj];
#pragma unroll
            for (int i = 0; i < 8; ++i) {
                const int mrow0 = m0 + wm + i * 16 + quad * 4;
                const int b_ = mrow0 >> 11, n0 = mrow0 & 2047;
                const int t32 = n0 >> 5;
                const int i16 = (n0 >> 4) & 1;
                const int quadpp = i16 * 2 + (quad >> 1);
                bf16x4 o;
#pragma unroll
                for (int r = 0; r < 4; ++r) o[r] = f2bf(acc[i][jb][r] + bv);
                *(bf16x4*)&qkvb[2 * QKVSZ + (size_t)(b_ * NHEADS + hh) * HEADEL +
                                (size_t)(t32 * 4 + fb) * 512 +
                                (quadpp * 16 + dl) * 8 + (quad & 1) * 4] = o;
            }
        }
    }
}

// ---------------------------------------------------------------------------
// Kernel 2: MFMA flash attention, zero in-loop sync, key-split-4, all-x32.
// XCD-aware block mapping (each XCD owns 4 (h,b) pairs -> 2 MB K/V in its
// L2); P packed via v_cvt_pk_bf16_f32; setprio around MFMA clusters.
// THIS ROUND: occupancy 2 -> 4 blocks/CU (launch_bounds(256,4)). Counters
// showed MfmaUtil 34 / VALUBusy 31 / Occupancy 16.6% -- latency-bound, not
// pipe-bound: the per-g serial chain (QK MFMA -> exp2/cvt -> PV MFMA) with
// only 2 waves/SIMD has nothing to hide under. VGPR 88 <= 128 cap, LDS
// 33 KB x 4 = 132 KB <= 160 KB, grid 1024 = exactly 4 blocks/CU.
// ---------------------------------------------------------------------------
__global__ __launch_bounds__(256, 4) void attn_mfma(
    const short* __restrict__ qkvb,  // Q(pre-scaled)|Kf|Vf bf16
    short* __restrict__ aob)         // [B,N,C] bf16
{
    __shared__ float Osm[2][4][4][4][64];  // [buf][g][fb][r][lane] = 32 KB
    __shared__ float Lsm[3][64];

    const int tid  = threadIdx.x;
    const int sp   = tid >> 6;        // key-split quarter
    const int lane = tid & 63;
    const int quad = lane >> 4;
    const int lid  = lane & 15;

    const int bid  = blockIdx.x;              // 0..1023
    const int xcd  = bid & 7;
    const int slot = bid >> 3;                // 0..127
    const int pair = xcd * 4 + (slot >> 5);   // 0..31
    const int qblk = slot & 31;
    const int h = pair & 15;
    const int b = pair >> 4;
    const int qbase = qblk * 64;

    const short* Qh = qkvb + (size_t)(b * NHEADS + h) * HEADEL;
    const short* Kf = Qh + QKVSZ;
    const short* Vf = qkvb + 2 * QKVSZ + (size_t)(b * NHEADS + h) * HEADEL;

    bf16x8 bQ[4][2];
#pragma unroll
    for (int g = 0; g < 4; ++g)
#pragma unroll
        for (int c = 0; c < 2; ++c)
            bQ[g][c] = *(const bf16x8*)&Qh[(size_t)(qbase + g * 16 + lid) * HDIM +
                                           c * 32 + quad * 8];

    f32x4 O[4][4];                    // [g][fb] O^T accum: row=d, col=q
    f32x4 L[4];                       // [g] row-sum accum (all rows equal)
#pragma unroll
    for (int g = 0; g < 4; ++g) {
        L[g] = (f32x4){0.f, 0.f, 0.f, 0.f};
#pragma unroll
        for (int fb = 0; fb < 4; ++fb) O[g][fb] = (f32x4){0.f, 0.f, 0.f, 0.f};
    }
    const bf16x8 ones8 = {(short)0x3F80, (short)0x3F80, (short)0x3F80, (short)0x3F80,
                          (short)0x3F80, (short)0x3F80, (short)0x3F80, (short)0x3F80};
    f32x4 Z = (f32x4){0.f, 0.f, 0.f, 0.f};
    asm volatile("" : "+v"(Z));       // pin: persistent zero C-operand

#pragma unroll 2
    for (int cc = 0; cc < SEQ / 128; ++cc) {      // 16 chunks of 32 keys
        const int t = sp * (SEQ / 128) + cc;
        bf16x8 aK[2][2];              // [tile c][c2]
#pragma unroll
        for (int c = 0; c < 2; ++c)
#pragma unroll
            for (int c2 = 0; c2 < 2; ++c2)
                aK[c][c2] = *(const bf16x8*)&Kf[(size_t)(t * 4 + c2 * 2 + c) * 512 +
                                                lane * 8];
        bf16x8 aV[4];
#pragma unroll
        for (int fb = 0; fb < 4; ++fb)
            aV[fb] = *(const bf16x8*)&Vf[(size_t)(t * 4 + fb) * 512 + lane * 8];

#pragma unroll
        for (int g = 0; g < 4; ++g) {
            f32x4 s0, s1;
            __builtin_amdgcn_s_setprio(1);
            s0 = __builtin_amdgcn_mfma_f32_16x16x32_bf16(aK[0][0], bQ[g][0], Z, 0, 0, 0);
            s1 = __builtin_amdgcn_mfma_f32_16x16x32_bf16(aK[1][0], bQ[g][0], Z, 0, 0, 0);
            s0 = __builtin_amdgcn_mfma_f32_16x16x32_bf16(aK[0][1], bQ[g][1], s0, 0, 0, 0);
            s1 = __builtin_amdgcn_mfma_f32_16x16x32_bf16(aK[1][1], bQ[g][1], s1, 0, 0, 0);
            __builtin_amdgcn_s_setprio(0);
            // P[j=quad*8+0..3] from tile0, P[j=+4..7] from tile1
            union { unsigned u[4]; bf16x8 v; } P;
            P.u[0] = cvt_pk_bf16(EXP2F(s0[0]), EXP2F(s0[1]));
            P.u[1] = cvt_pk_bf16(EXP2F(s0[2]), EXP2F(s0[3]));
            P.u[2] = cvt_pk_bf16(EXP2F(s1[0]), EXP2F(s1[1]));
            P.u[3] = cvt_pk_bf16(EXP2F(s1[2]), EXP2F(s1[3]));
            __builtin_amdgcn_s_setprio(1);
            L[g] = __builtin_amdgcn_mfma_f32_16x16x32_bf16(ones8, P.v, L[g], 0, 0, 0);
#pragma unroll
            for (int fb = 0; fb < 4; ++fb)
                O[g][fb] = __builtin_amdgcn_mfma_f32_16x16x32_bf16(
                    aV[fb], P.v, O[g][fb], 0, 0, 0);
            __builtin_amdgcn_s_setprio(0);
        }
    }

    // ---- 2-stage split-4 combine (pure sums; no max tracking) ----
    if (sp != 0 && quad == 0)
#pragma unroll
        for (int g = 0; g < 4; ++g) Lsm[sp - 1][g * 16 + lid] = L[g][0];

    if (sp == 1 || sp == 3) {         // stage A publish
        const int buf = sp >> 1;
#pragma unroll
        for (int g = 0; g < 4; ++g)
#pragma unroll
            for (int fb = 0; fb < 4; ++fb)
#pragma unroll
                for (int r = 0; r < 4; ++r)
                    Osm[buf][g][fb][r][lane] = O[g][fb][r];
    }
    __syncthreads();
    if (sp == 0 || sp == 2) {         // stage A combine
        const int buf = sp >> 1;
#pragma unroll
        for (int g = 0; g < 4; ++g)
#pragma unroll
            for (int fb = 0; fb < 4; ++fb)
#pragma unroll
                for (int r = 0; r < 4; ++r)
                    O[g][fb][r] += Osm[buf][g][fb][r][lane];
    }
    __syncthreads();
    if (sp == 2) {                    // stage B publish
#pragma unroll
        for (int g = 0; g < 4; ++g)
#pragma unroll
            for (int fb = 0; fb < 4; ++fb)
#pragma unroll
                for (int r = 0; r < 4; ++r)
                    Osm[0][g][fb][r][lane] = O[g][fb][r];
    }
    __syncthreads();
    if (sp == 0) {                    // final combine + store
#pragma unroll
        for (int g = 0; g < 4; ++g) {
            const float lt = L[g][0] + Lsm[0][g * 16 + lid] +
                             Lsm[1][g * 16 + lid] + Lsm[2][g * 16 + lid];
            const float inv = 1.f / lt;
            const int n = qbase + g * 16 + lid;
            size_t base = ((size_t)(b * SEQ + n)) * DIMC + h * HDIM;
#pragma unroll
            for (int fb = 0; fb < 4; ++fb) {
                bf16x4 o;
#pragma unroll
                for (int r = 0; r < 4; ++r)
                    o[r] = f2bf((O[g][fb][r] + Osm[0][g][fb][r][lane]) * inv);
                *(bf16x4*)&aob[base + fb * 16 + quad * 4] = o;
            }
        }
    }
}

// ---------------------------------------------------------------------------
// Kernel 3: out = ao_bf @ w_proj_bf^T + b_proj (MFMA, BK=64), fp32 out.
// ---------------------------------------------------------------------------
__global__ __launch_bounds__(256, 2) void proj_mfma(
    const short* __restrict__ ab,    // [4096][1024] bf16
    const short* __restrict__ wb,    // [1024][1024] bf16
    const float* __restrict__ bias,  // [1024] fp32
    float* __restrict__ out)         // [4096][1024] fp32
{
    __shared__ __attribute__((aligned(16))) short Asm[2 * 64 * 32];
    __shared__ __attribute__((aligned(16))) short Bsm[2 * 128 * 32];

    const int tid = threadIdx.x;
    const int m0 = blockIdx.y * 64;
    const int j0 = blockIdx.x * 128;

    const int lane = tid & 63;
    const int w    = tid >> 6;
    const int quad = lane >> 4;
    const int lid  = lane & 15;
    const int wm = (w >> 1) * 32, wn = (w & 1) * 64;

    const int srow = lane >> 2;
    const int skc  = (lane & 3) * 8;

    f32x4 acc[2][4];
#pragma unroll
    for (int i = 0; i < 2; ++i)
#pragma unroll
        for (int j = 0; j < 4; ++j) acc[i][j] = (f32x4){0.f, 0.f, 0.f, 0.f};

    for (int k0 = 0; k0 < 1024; k0 += 64) {
        __syncthreads();
#pragma unroll
        for (int u = 0; u < 2; ++u) {
            const int combo = w * 2 + u;        // 0..7
            const int hh = combo >> 2, rb = combo & 3;
            const int row = rb * 16 + srow;
            gload16(&ab[(size_t)(m0 + row) * 1024 + k0 + hh * 32 + skc],
                    &Asm[hh * 2048 + row * 32 + skc]);
        }
#pragma unroll
        for (int u = 0; u < 4; ++u) {
            const int combo = w * 4 + u;        // 0..15
            const int hh = combo >> 3, rb = combo & 7;
            const int row = rb * 16 + srow;
            gload16(&wb[(size_t)(j0 + row) * 1024 + k0 + hh * 32 + skc],
                    &Bsm[hh * 4096 + row * 32 + skc]);
        }
        __syncthreads();

#pragma unroll
        for (int hh = 0; hh < 2; ++hh) {
            bf16x8 af[2], bfr[4];
#pragma unroll
            for (int i = 0; i < 2; ++i)
                af[i] = *(const bf16x8*)&Asm[hh * 2048 + (wm + i * 16 + lid) * 32 + quad * 8];
#pragma unroll
            for (int j = 0; j < 4; ++j)
                bfr[j] = *(const bf16x8*)&Bsm[hh * 4096 + (wn + j * 16 + lid) * 32 + quad * 8];
#pragma unroll
            for (int i = 0; i < 2; ++i)
#pragma unroll
                for (int j = 0; j < 4; ++j)
                    acc[i][j] = __builtin_amdgcn_mfma_f32_16x16x32_bf16(
                        af[i], bfr[j], acc[i][j], 0, 0, 0);
        }
    }

#pragma unroll
    for (int jb = 0; jb < 4; ++jb) {
        const int jj = j0 + wn + jb * 16 + lid;
        const float bv = bias[jj];
#pragma unroll
        for (int i = 0; i < 2; ++i)
#pragma unroll
            for (int r = 0; r < 4; ++r) {
                const int mrow = m0 + wm + i * 16 + quad * 4 + r;
                out[(size_t)mrow * DIMC + jj] = acc[i][jb][r] + bv;
            }
    }
}

// ---------------------------------------------------------------------------
extern "C" void kernel_launch(void* const* d_in, const int* in_sizes, int n_in,
                              void* d_out, int out_size, void* d_ws, size_t ws_size,
                              hipStream_t stream) {
    const float* x      = (const float*)d_in[0];
    const float* w_qkv  = (const float*)d_in[1];
    const float* b_qkv  = (const float*)d_in[2];
    const float* w_proj = (const float*)d_in[3];
    const float* b_proj = (const float*)d_in[4];
    float* out = (float*)d_out;

    short* qkvb   = (short*)d_ws;                  // Q|Kf|Vf: 3*QKVSZ
    short* xb     = qkvb + 3 * QKVSZ;
    short* wqkvb  = xb + (size_t)MTOT * DIMC;
    short* wprojb = wqkvb + (size_t)QKVN * DIMC;
    short* aob    = wprojb + (size_t)DIMC * DIMC;

    hipFuncSetAttribute((const void*)qkv_mfma,
                        hipFuncAttributeMaxDynamicSharedMemorySize, 131072);

    cast_all<<<NXB + NWQB + NWPB, 256, 0, stream>>>(x, w_qkv, w_proj,
                                                    xb, wqkvb, wprojb);

    qkv_mfma<<<192, 512, 131072, stream>>>(xb, wqkvb, b_qkv, qkvb);

    attn_mfma<<<BATCH * NHEADS * (SEQ / 64), 256, 0, stream>>>(qkvb, aob);

    dim3 g3(DIMC / 128, MTOT / 64);                // 8 x 64 = 512
    proj_mfma<<<g3, 256, 0, stream>>>(aob, wprojb, b_proj, out);
}

// Round 8
// 172.488 us; speedup vs baseline: 2.1655x; 2.1655x over previous
//
#include <hip/hip_runtime.h>
#include <math.h>

#define DIMC   1024
#define NHEADS 16
#define HDIM   64
#define BATCH  2
#define SEQ    2048

#define MTOT   (BATCH * SEQ)          // 4096 rows
#define QKVN   (3 * DIMC)             // 3072
#define QKVSZ  ((size_t)BATCH * NHEADS * SEQ * HDIM)  // 4194304 elems per tensor
#define HEADEL ((size_t)SEQ * HDIM)   // 131072 shorts per head

// SCALE * log2(e): folded into Q at the qkv epilogue so attention uses exp2.
#define QSCALE 0.18033688011112042f

typedef __attribute__((ext_vector_type(8))) short bf16x8;
typedef __attribute__((ext_vector_type(4))) short bf16x4;
typedef __attribute__((ext_vector_type(4))) float f32x4;

static __device__ inline short f2bf(float f) {
    union { float f; unsigned u; } v; v.f = f;
    unsigned r = v.u + 0x7fffu + ((v.u >> 16) & 1u);   // RNE
    return (short)(r >> 16);
}

// packed f32x2 -> bf16x2 (RNE), low16 = lo, high16 = hi. No builtin on gfx950.
static __device__ inline unsigned cvt_pk_bf16(float lo, float hi) {
    unsigned r;
    asm("v_cvt_pk_bf16_f32 %0, %1, %2" : "=v"(r) : "v"(lo), "v"(hi));
    return r;
}

#if __has_builtin(__builtin_amdgcn_exp2f)
#define EXP2F(x) __builtin_amdgcn_exp2f(x)
#else
#define EXP2F(x) exp2f(x)
#endif

// ---------------------------------------------------------------------------
// fused fp32 -> bf16 cast of x, w_qkv, w_proj (memory-bound, one launch)
// ---------------------------------------------------------------------------
#define NXB  (MTOT * DIMC / 2048)     // 2048 blocks
#define NWQB (QKVN * DIMC / 2048)     // 1536
#define NWPB (DIMC * DIMC / 2048)     // 512

__global__ __launch_bounds__(256) void cast_all(
    const float* __restrict__ x,  const float* __restrict__ wq,
    const float* __restrict__ wp, short* __restrict__ xb,
    short* __restrict__ wqb, short* __restrict__ wpb)
{
    const float* in; short* out; int base;
    int bid = blockIdx.x;
    if (bid < NXB)              { in = x;  out = xb;  base = bid; }
    else if (bid < NXB + NWQB)  { in = wq; out = wqb; base = bid - NXB; }
    else                        { in = wp; out = wpb; base = bid - NXB - NWQB; }
    int i = (base * 256 + threadIdx.x) * 8;
    float4 a = *(const float4*)&in[i];
    float4 b = *(const float4*)&in[i + 4];
    bf16x8 o;
    o[0] = f2bf(a.x); o[1] = f2bf(a.y); o[2] = f2bf(a.z); o[3] = f2bf(a.w);
    o[4] = f2bf(b.x); o[5] = f2bf(b.y); o[6] = f2bf(b.z); o[7] = f2bf(b.w);
    *(bf16x8*)&out[i] = o;
}

// ---------------------------------------------------------------------------
// async global->LDS, 16B per lane
// ---------------------------------------------------------------------------
__device__ __forceinline__ void gload16(const void* g, void* l) {
    __builtin_amdgcn_global_load_lds(
        (const __attribute__((address_space(1))) unsigned*)g,
        (__attribute__((address_space(3))) unsigned*)l, 16, 0, 0);
}

#define BAR() do { __builtin_amdgcn_s_barrier(); \
                   __builtin_amdgcn_sched_barrier(0); } while (0)
#define VWAIT8() asm volatile("s_waitcnt vmcnt(8)" ::: "memory")
#define VWAIT0() asm volatile("s_waitcnt vmcnt(0)" ::: "memory")

// ---------------------------------------------------------------------------
// Kernel 1: qkv GEMM, 256x256 tile, BK=64, 8 waves (2M x 4N).
// Round-5 structure (best measured): counted-vmcnt double-buffer, all 8
// next-tile gloads at tile top, vmcnt(8) tile-granular wait, 2 barriers/tile,
// B-fragment reuse (24 ds_read_b128/wave/tile).
// Bank swizzle: LDS[r][g^(r&7)] = G[r][g] on 16B granules, applied on the
// global source (gload_lds dest stays linear) and on the ds_read address.
// ---------------------------------------------------------------------------
__device__ __forceinline__ void stage_panel(const short* __restrict__ src,
                                            int row0, int k0,
                                            short* dst, int tid)
{
#pragma unroll
    for (int u = 0; u < 2; ++u) {
        const int gidx = u * 512 + tid;        // 16B granule index in panel
        const int rl   = gidx >> 3;            // row in panel (0..127)
        const int cc   = gidx & 7;             // 16B col granule (0..7)
        gload16(&src[(size_t)(row0 + rl) * 1024 + k0 + ((cc ^ (rl & 7)) << 3)],
                &dst[(size_t)gidx << 3]);      // linear LDS dest
    }
}

__device__ __forceinline__ void load_b(const short* Bs, int wn, int nh,
                                       int lid, int quad, bf16x8 (&bfr)[2][2])
{
#pragma unroll
    for (int j2 = 0; j2 < 2; ++j2) {
        const int rb = wn + (nh * 2 + j2) * 16 + lid;
#pragma unroll
        for (int kk = 0; kk < 2; ++kk)
            bfr[j2][kk] = *(const bf16x8*)
                &Bs[rb * 64 + (((kk * 4 + quad) ^ (rb & 7)) << 3)];
    }
}

template<int MH>
__device__ __forceinline__ void half_compute(
    const short* As, int wm, int lid, int quad,
    const bf16x8 (&b0)[2][2], const bf16x8 (&b1)[2][2],
    f32x4 (&acc)[8][4])
{
    bf16x8 af[4][2];
#pragma unroll
    for (int i2 = 0; i2 < 4; ++i2) {
        const int r = wm + (MH * 4 + i2) * 16 + lid;
#pragma unroll
        for (int kk = 0; kk < 2; ++kk)
            af[i2][kk] = *(const bf16x8*)
                &As[r * 64 + (((kk * 4 + quad) ^ (r & 7)) << 3)];
    }
    __builtin_amdgcn_s_setprio(1);
#pragma unroll
    for (int i2 = 0; i2 < 4; ++i2)
#pragma unroll
        for (int kk = 0; kk < 2; ++kk) {
            acc[MH * 4 + i2][0] = __builtin_amdgcn_mfma_f32_16x16x32_bf16(
                af[i2][kk], b0[0][kk], acc[MH * 4 + i2][0], 0, 0, 0);
            acc[MH * 4 + i2][1] = __builtin_amdgcn_mfma_f32_16x16x32_bf16(
                af[i2][kk], b0[1][kk], acc[MH * 4 + i2][1], 0, 0, 0);
            acc[MH * 4 + i2][2] = __builtin_amdgcn_mfma_f32_16x16x32_bf16(
                af[i2][kk], b1[0][kk], acc[MH * 4 + i2][2], 0, 0, 0);
            acc[MH * 4 + i2][3] = __builtin_amdgcn_mfma_f32_16x16x32_bf16(
                af[i2][kk], b1[1][kk], acc[MH * 4 + i2][3], 0, 0, 0);
        }
    __builtin_amdgcn_s_setprio(0);
}

__global__ __launch_bounds__(512, 2) void qkv_mfma(
    const short* __restrict__ xb,    // [4096][1024] bf16
    const short* __restrict__ wb,    // [3072][1024] bf16
    const float* __restrict__ bias,  // [3072] fp32
    short* __restrict__ qkvb)        // Q|Kf|Vf bf16
{
    extern __shared__ short lds[];   // [2][A 256*64 | B 256*64] = 128 KiB

    const int tid = threadIdx.x;
    // bijective XCD-chunked swizzle: nwg=192, 192%8==0
    const int T  = (blockIdx.x & 7) * 24 + (blockIdx.x >> 3);
    const int m0 = (T / 12) * 256;
    const int j0 = (T % 12) * 256;

    const int lane = tid & 63;
    const int w    = tid >> 6;
    const int quad = lane >> 4;
    const int lid  = lane & 15;
    const int wm = (w >> 2) * 128;   // wave_m in {0,1}
    const int wn = (w & 3) * 64;     // wave_n in {0..3}

    f32x4 acc[8][4];
#pragma unroll
    for (int i = 0; i < 8; ++i)
#pragma unroll
        for (int j = 0; j < 4; ++j) acc[i][j] = (f32x4){0.f, 0.f, 0.f, 0.f};

    // prologue: stage K-tile 0 into buf0
    stage_panel(xb, m0,       0, lds,                 tid);
    stage_panel(xb, m0 + 128, 0, lds + 8192,          tid);
    stage_panel(wb, j0,       0, lds + 32768,         tid);
    stage_panel(wb, j0 + 128, 0, lds + 32768 + 8192,  tid);

#pragma unroll 2
    for (int kt = 0; kt < 15; ++kt) {
        const int cb = (kt & 1) << 14;
        const int nb = (~kt & 1) << 14;
        const int k1 = (kt + 1) << 6;
        const short* Ac = lds + cb;
        const short* Bc = lds + 32768 + cb;
        short* An = lds + nb;
        short* Bn = lds + 32768 + nb;

        // issue ALL next-tile panel loads up front (8 per thread)
        stage_panel(xb, m0,       k1, An,        tid);
        stage_panel(xb, m0 + 128, k1, An + 8192, tid);
        stage_panel(wb, j0,       k1, Bn,        tid);
        stage_panel(wb, j0 + 128, k1, Bn + 8192, tid);

        // retire current tile's 8 loads; keep next tile's 8 in flight
        VWAIT8(); BAR();
        {
            bf16x8 b0[2][2], b1[2][2];
            load_b(Bc, wn, 0, lid, quad, b0);
            load_b(Bc, wn, 1, lid, quad, b1);
            half_compute<0>(Ac, wm, lid, quad, b0, b1, acc);
            half_compute<1>(Ac, wm, lid, quad, b0, b1, acc);
        }
        BAR();                       // all waves done reading cb before it is
                                     // overwritten by next iteration's stage
    }
    // peeled last K-tile (kt=15, buf1, nothing left to stage)
    {
        const short* Ac = lds + 16384;
        const short* Bc = lds + 32768 + 16384;
        VWAIT0(); BAR();
        bf16x8 b0[2][2], b1[2][2];
        load_b(Bc, wn, 0, lid, quad, b0);
        load_b(Bc, wn, 1, lid, quad, b1);
        half_compute<0>(Ac, wm, lid, quad, b0, b1, acc);
        half_compute<1>(Ac, wm, lid, quad, b0, b1, acc);
    }

    // ---- epilogue ----
    const int s = j0 >> 10;            // uniform: 0:q 1:k 2:v

    if (s == 0) {
#pragma unroll
        for (int jb = 0; jb < 4; ++jb) {
            const int jj = j0 + wn + jb * 16 + lid;
            const int hh = (jj & 1023) >> 6;
            const int dd = jj & 63;
            const float bv = bias[jj];
#pragma unroll
            for (int i = 0; i < 8; ++i)
#pragma unroll
                for (int r = 0; r < 4; ++r) {
                    const int mrow = m0 + wm + i * 16 + quad * 4 + r;
                    const int b_ = mrow >> 11, nn = mrow & 2047;
                    qkvb[((size_t)(b_ * NHEADS + hh) * SEQ + nn) * HDIM + dd] =
                        f2bf((acc[i][jb][r] + bv) * QSCALE);
                }
        }
    } else if (s == 1) {
        // K: permuted fragment-major.
#pragma unroll
        for (int jb = 0; jb < 4; ++jb) {
            const int jj = j0 + wn + jb * 16 + lid;
            const int hh = (jj & 1023) >> 6;
            const int dd = jj & 63;
            const int c2 = dd >> 5;
            const int qd = (dd >> 3) & 3;
            const int jo = dd & 7;
            const float bv = bias[jj];
#pragma unroll
            for (int i = 0; i < 8; ++i) {
                const int mrow0 = m0 + wm + i * 16;
                const int b_ = mrow0 >> 11;
                const int n0 = mrow0 & 2047;
                const int t32 = n0 >> 5;
                const int i16 = (n0 >> 4) & 1;
                const int c = quad & 1;
                const int lidb = (i16 * 2 + (quad >> 1)) * 4;
                size_t base = QKVSZ + (size_t)(b_ * NHEADS + hh) * HEADEL +
                              (size_t)(t32 * 4 + c2 * 2 + c) * 512 +
                              (qd * 16 + lidb) * 8 + jo;
#pragma unroll
                for (int r = 0; r < 4; ++r)
                    qkvb[base + r * 8] = f2bf(acc[i][jb][r] + bv);
            }
        }
    } else {
        // V: x32-A fragment-major.
#pragma unroll
        for (int jb = 0; jb < 4; ++jb) {
            const int jj = j0 + wn + jb * 16 + lid;
            const int hh = (jj & 1023) >> 6;
            const int dd = jj & 63;
            const int fb = dd >> 4;
            const int dl = dd & 15;
            const float bv = bias[jj];
#pragma unroll
            for (int i = 0; i < 8; ++i) {
                const int mrow0 = m0 + wm + i * 16 + quad * 4;
                const int b_ = mrow0 >> 11, n0 = mrow0 & 2047;
                const int t32 = n0 >> 5;
                const int i16 = (n0 >> 4) & 1;
                const int quadpp = i16 * 2 + (quad >> 1);
                bf16x4 o;
#pragma unroll
                for (int r = 0; r < 4; ++r) o[r] = f2bf(acc[i][jb][r] + bv);
                *(bf16x4*)&qkvb[2 * QKVSZ + (size_t)(b_ * NHEADS + hh) * HEADEL +
                                (size_t)(t32 * 4 + fb) * 512 +
                                (quadpp * 16 + dl) * 8 + (quad & 1) * 4] = o;
            }
        }
    }
}

// ---------------------------------------------------------------------------
// Kernel 2: MFMA flash attention, zero in-loop sync, key-split-4, all-x32.
// XCD-aware block mapping; cvt_pk P-pack; setprio. launch_bounds(256,2):
// round-7 lesson -- forcing (256,4) clamped VGPR to 64 < accumulator
// footprint (~88) -> full scratch spill, 5.6x slower. Never clamp below
// live state; raise occupancy via resources instead.
// THIS ROUND: LDS shrink 33.8 -> 17.2 KB (single combine buffer, 5-step
// barrier sequence) so 4+ blocks/CU fit LDS-wise at unchanged VGPR.
// ---------------------------------------------------------------------------
__global__ __launch_bounds__(256, 2) void attn_mfma(
    const short* __restrict__ qkvb,  // Q(pre-scaled)|Kf|Vf bf16
    short* __restrict__ aob)         // [B,N,C] bf16
{
    __shared__ float Osm[4][4][4][64];     // [g][fb][r][lane] = 16 KB (single buf)
    __shared__ float Lsm[3][64];

    const int tid  = threadIdx.x;
    const int sp   = tid >> 6;        // key-split quarter
    const int lane = tid & 63;
    const int quad = lane >> 4;
    const int lid  = lane & 15;

    const int bid  = blockIdx.x;              // 0..1023
    const int xcd  = bid & 7;
    const int slot = bid >> 3;                // 0..127
    const int pair = xcd * 4 + (slot >> 5);   // 0..31
    const int qblk = slot & 31;
    const int h = pair & 15;
    const int b = pair >> 4;
    const int qbase = qblk * 64;

    const short* Qh = qkvb + (size_t)(b * NHEADS + h) * HEADEL;
    const short* Kf = Qh + QKVSZ;
    const short* Vf = qkvb + 2 * QKVSZ + (size_t)(b * NHEADS + h) * HEADEL;

    bf16x8 bQ[4][2];
#pragma unroll
    for (int g = 0; g < 4; ++g)
#pragma unroll
        for (int c = 0; c < 2; ++c)
            bQ[g][c] = *(const bf16x8*)&Qh[(size_t)(qbase + g * 16 + lid) * HDIM +
                                           c * 32 + quad * 8];

    f32x4 O[4][4];                    // [g][fb] O^T accum: row=d, col=q
    f32x4 L[4];                       // [g] row-sum accum (all rows equal)
#pragma unroll
    for (int g = 0; g < 4; ++g) {
        L[g] = (f32x4){0.f, 0.f, 0.f, 0.f};
#pragma unroll
        for (int fb = 0; fb < 4; ++fb) O[g][fb] = (f32x4){0.f, 0.f, 0.f, 0.f};
    }
    const bf16x8 ones8 = {(short)0x3F80, (short)0x3F80, (short)0x3F80, (short)0x3F80,
                          (short)0x3F80, (short)0x3F80, (short)0x3F80, (short)0x3F80};

#pragma unroll 2
    for (int cc = 0; cc < SEQ / 128; ++cc) {      // 16 chunks of 32 keys
        const int t = sp * (SEQ / 128) + cc;
        bf16x8 aK[2][2];              // [tile c][c2]
#pragma unroll
        for (int c = 0; c < 2; ++c)
#pragma unroll
            for (int c2 = 0; c2 < 2; ++c2)
                aK[c][c2] = *(const bf16x8*)&Kf[(size_t)(t * 4 + c2 * 2 + c) * 512 +
                                                lane * 8];
        bf16x8 aV[4];
#pragma unroll
        for (int fb = 0; fb < 4; ++fb)
            aV[fb] = *(const bf16x8*)&Vf[(size_t)(t * 4 + fb) * 512 + lane * 8];

#pragma unroll
        for (int g = 0; g < 4; ++g) {
            f32x4 s0 = (f32x4){0.f, 0.f, 0.f, 0.f};
            f32x4 s1 = (f32x4){0.f, 0.f, 0.f, 0.f};
            __builtin_amdgcn_s_setprio(1);
            s0 = __builtin_amdgcn_mfma_f32_16x16x32_bf16(aK[0][0], bQ[g][0], s0, 0, 0, 0);
            s1 = __builtin_amdgcn_mfma_f32_16x16x32_bf16(aK[1][0], bQ[g][0], s1, 0, 0, 0);
            s0 = __builtin_amdgcn_mfma_f32_16x16x32_bf16(aK[0][1], bQ[g][1], s0, 0, 0, 0);
            s1 = __builtin_amdgcn_mfma_f32_16x16x32_bf16(aK[1][1], bQ[g][1], s1, 0, 0, 0);
            __builtin_amdgcn_s_setprio(0);
            // P[j=quad*8+0..3] from tile0, P[j=+4..7] from tile1
            union { unsigned u[4]; bf16x8 v; } P;
            P.u[0] = cvt_pk_bf16(EXP2F(s0[0]), EXP2F(s0[1]));
            P.u[1] = cvt_pk_bf16(EXP2F(s0[2]), EXP2F(s0[3]));
            P.u[2] = cvt_pk_bf16(EXP2F(s1[0]), EXP2F(s1[1]));
            P.u[3] = cvt_pk_bf16(EXP2F(s1[2]), EXP2F(s1[3]));
            __builtin_amdgcn_s_setprio(1);
            L[g] = __builtin_amdgcn_mfma_f32_16x16x32_bf16(ones8, P.v, L[g], 0, 0, 0);
#pragma unroll
            for (int fb = 0; fb < 4; ++fb)
                O[g][fb] = __builtin_amdgcn_mfma_f32_16x16x32_bf16(
                    aV[fb], P.v, O[g][fb], 0, 0, 0);
            __builtin_amdgcn_s_setprio(0);
        }
    }

    // ---- split-4 combine, single 16 KB buffer, 5 barrier steps ----
    if (sp != 0 && quad == 0)
#pragma unroll
        for (int g = 0; g < 4; ++g) Lsm[sp - 1][g * 16 + lid] = L[g][0];

    if (sp == 1) {                    // step 1: sp1 publish
#pragma unroll
        for (int g = 0; g < 4; ++g)
#pragma unroll
            for (int fb = 0; fb < 4; ++fb)
#pragma unroll
                for (int r = 0; r < 4; ++r)
                    Osm[g][fb][r][lane] = O[g][fb][r];
    }
    __syncthreads();
    if (sp == 0) {                    // step 2: sp0 += sp1
#pragma unroll
        for (int g = 0; g < 4; ++g)
#pragma unroll
            for (int fb = 0; fb < 4; ++fb)
#pragma unroll
                for (int r = 0; r < 4; ++r)
                    O[g][fb][r] += Osm[g][fb][r][lane];
    }
    __syncthreads();
    if (sp == 3) {                    // step 3: sp3 publish
#pragma unroll
        for (int g = 0; g < 4; ++g)
#pragma unroll
            for (int fb = 0; fb < 4; ++fb)
#pragma unroll
                for (int r = 0; r < 4; ++r)
                    Osm[g][fb][r][lane] = O[g][fb][r];
    }
    __syncthreads();
    if (sp == 2) {                    // step 4: sp2 += sp3
#pragma unroll
        for (int g = 0; g < 4; ++g)
#pragma unroll
            for (int fb = 0; fb < 4; ++fb)
#pragma unroll
                for (int r = 0; r < 4; ++r)
                    O[g][fb][r] += Osm[g][fb][r][lane];
    }
    __syncthreads();
    if (sp == 2) {                    // step 5: sp2 publish (sp2+sp3)
#pragma unroll
        for (int g = 0; g < 4; ++g)
#pragma unroll
            for (int fb = 0; fb < 4; ++fb)
#pragma unroll
                for (int r = 0; r < 4; ++r)
                    Osm[g][fb][r][lane] = O[g][fb][r];
    }
    __syncthreads();
    if (sp == 0) {                    // final: sp0 has sp0+sp1; add (sp2+sp3)
#pragma unroll
        for (int g = 0; g < 4; ++g) {
            const float lt = L[g][0] + Lsm[0][g * 16 + lid] +
                             Lsm[1][g * 16 + lid] + Lsm[2][g * 16 + lid];
            const float inv = 1.f / lt;
            const int n = qbase + g * 16 + lid;
            size_t base = ((size_t)(b * SEQ + n)) * DIMC + h * HDIM;
#pragma unroll
            for (int fb = 0; fb < 4; ++fb) {
                bf16x4 o;
#pragma unroll
                for (int r = 0; r < 4; ++r)
                    o[r] = f2bf((O[g][fb][r] + Osm[g][fb][r][lane]) * inv);
                *(bf16x4*)&aob[base + fb * 16 + quad * 4] = o;
            }
        }
    }
}

// ---------------------------------------------------------------------------
// Kernel 3: out = ao_bf @ w_proj_bf^T + b_proj (MFMA, BK=64), fp32 out.
// ---------------------------------------------------------------------------
__global__ __launch_bounds__(256, 2) void proj_mfma(
    const short* __restrict__ ab,    // [4096][1024] bf16
    const short* __restrict__ wb,    // [1024][1024] bf16
    const float* __restrict__ bias,  // [1024] fp32
    float* __restrict__ out)         // [4096][1024] fp32
{
    __shared__ __attribute__((aligned(16))) short Asm[2 * 64 * 32];
    __shared__ __attribute__((aligned(16))) short Bsm[2 * 128 * 32];

    const int tid = threadIdx.x;
    const int m0 = blockIdx.y * 64;
    const int j0 = blockIdx.x * 128;

    const int lane = tid & 63;
    const int w    = tid >> 6;
    const int quad = lane >> 4;
    const int lid  = lane & 15;
    const int wm = (w >> 1) * 32, wn = (w & 1) * 64;

    const int srow = lane >> 2;
    const int skc  = (lane & 3) * 8;

    f32x4 acc[2][4];
#pragma unroll
    for (int i = 0; i < 2; ++i)
#pragma unroll
        for (int j = 0; j < 4; ++j) acc[i][j] = (f32x4){0.f, 0.f, 0.f, 0.f};

    for (int k0 = 0; k0 < 1024; k0 += 64) {
        __syncthreads();
#pragma unroll
        for (int u = 0; u < 2; ++u) {
            const int combo = w * 2 + u;        // 0..7
            const int hh = combo >> 2, rb = combo & 3;
            const int row = rb * 16 + srow;
            gload16(&ab[(size_t)(m0 + row) * 1024 + k0 + hh * 32 + skc],
                    &Asm[hh * 2048 + row * 32 + skc]);
        }
#pragma unroll
        for (int u = 0; u < 4; ++u) {
            const int combo = w * 4 + u;        // 0..15
            const int hh = combo >> 3, rb = combo & 7;
            const int row = rb * 16 + srow;
            gload16(&wb[(size_t)(j0 + row) * 1024 + k0 + hh * 32 + skc],
                    &Bsm[hh * 4096 + row * 32 + skc]);
        }
        __syncthreads();

#pragma unroll
        for (int hh = 0; hh < 2; ++hh) {
            bf16x8 af[2], bfr[4];
#pragma unroll
            for (int i = 0; i < 2; ++i)
                af[i] = *(const bf16x8*)&Asm[hh * 2048 + (wm + i * 16 + lid) * 32 + quad * 8];
#pragma unroll
            for (int j = 0; j < 4; ++j)
                bfr[j] = *(const bf16x8*)&Bsm[hh * 4096 + (wn + j * 16 + lid) * 32 + quad * 8];
#pragma unroll
            for (int i = 0; i < 2; ++i)
#pragma unroll
                for (int j = 0; j < 4; ++j)
                    acc[i][j] = __builtin_amdgcn_mfma_f32_16x16x32_bf16(
                        af[i], bfr[j], acc[i][j], 0, 0, 0);
        }
    }

#pragma unroll
    for (int jb = 0; jb < 4; ++jb) {
        const int jj = j0 + wn + jb * 16 + lid;
        const float bv = bias[jj];
#pragma unroll
        for (int i = 0; i < 2; ++i)
#pragma unroll
            for (int r = 0; r < 4; ++r) {
                const int mrow = m0 + wm + i * 16 + quad * 4 + r;
                out[(size_t)mrow * DIMC + jj] = acc[i][jb][r] + bv;
            }
    }
}

// ---------------------------------------------------------------------------
extern "C" void kernel_launch(void* const* d_in, const int* in_sizes, int n_in,
                              void* d_out, int out_size, void* d_ws, size_t ws_size,
                              hipStream_t stream) {
    const float* x      = (const float*)d_in[0];
    const float* w_qkv  = (const float*)d_in[1];
    const float* b_qkv  = (const float*)d_in[2];
    const float* w_proj = (const float*)d_in[3];
    const float* b_proj = (const float*)d_in[4];
    float* out = (float*)d_out;

    short* qkvb   = (short*)d_ws;                  // Q|Kf|Vf: 3*QKVSZ
    short* xb     = qkvb + 3 * QKVSZ;
    short* wqkvb  = xb + (size_t)MTOT * DIMC;
    short* wprojb = wqkvb + (size_t)QKVN * DIMC;
    short* aob    = wprojb + (size_t)DIMC * DIMC;

    hipFuncSetAttribute((const void*)qkv_mfma,
                        hipFuncAttributeMaxDynamicSharedMemorySize, 131072);

    cast_all<<<NXB + NWQB + NWPB, 256, 0, stream>>>(x, w_qkv, w_proj,
                                                    xb, wqkvb, wprojb);

    qkv_mfma<<<192, 512, 131072, stream>>>(xb, wqkvb, b_qkv, qkvb);

    attn_mfma<<<BATCH * NHEADS * (SEQ / 64), 256, 0, stream>>>(qkvb, aob);

    dim3 g3(DIMC / 128, MTOT / 64);                // 8 x 64 = 512
    proj_mfma<<<g3, 256, 0, stream>>>(aob, wprojb, b_proj, out);
}

// Round 9
// 165.421 us; speedup vs baseline: 2.2580x; 1.0427x over previous
//
#include <hip/hip_runtime.h>
#include <math.h>

#define DIMC   1024
#define NHEADS 16
#define HDIM   64
#define BATCH  2
#define SEQ    2048

#define MTOT   (BATCH * SEQ)          // 4096 rows
#define QKVN   (3 * DIMC)             // 3072
#define QKVSZ  ((size_t)BATCH * NHEADS * SEQ * HDIM)  // 4194304 elems per tensor
#define HEADEL ((size_t)SEQ * HDIM)   // 131072 shorts per head

// SCALE * log2(e): folded into Q at the qkv epilogue so attention uses exp2.
#define QSCALE 0.18033688011112042f

typedef __attribute__((ext_vector_type(8))) short bf16x8;
typedef __attribute__((ext_vector_type(4))) short bf16x4;
typedef __attribute__((ext_vector_type(4))) float f32x4;

static __device__ inline short f2bf(float f) {
    union { float f; unsigned u; } v; v.f = f;
    unsigned r = v.u + 0x7fffu + ((v.u >> 16) & 1u);   // RNE
    return (short)(r >> 16);
}

// packed f32x2 -> bf16x2 (RNE), low16 = lo, high16 = hi. No builtin on gfx950.
static __device__ inline unsigned cvt_pk_bf16(float lo, float hi) {
    unsigned r;
    asm("v_cvt_pk_bf16_f32 %0, %1, %2" : "=v"(r) : "v"(lo), "v"(hi));
    return r;
}

#if __has_builtin(__builtin_amdgcn_exp2f)
#define EXP2F(x) __builtin_amdgcn_exp2f(x)
#else
#define EXP2F(x) exp2f(x)
#endif

// ---------------------------------------------------------------------------
// fused fp32 -> bf16 cast of x, w_qkv, w_proj (memory-bound, one launch)
// ---------------------------------------------------------------------------
#define NXB  (MTOT * DIMC / 2048)     // 2048 blocks
#define NWQB (QKVN * DIMC / 2048)     // 1536
#define NWPB (DIMC * DIMC / 2048)     // 512

__global__ __launch_bounds__(256) void cast_all(
    const float* __restrict__ x,  const float* __restrict__ wq,
    const float* __restrict__ wp, short* __restrict__ xb,
    short* __restrict__ wqb, short* __restrict__ wpb)
{
    const float* in; short* out; int base;
    int bid = blockIdx.x;
    if (bid < NXB)              { in = x;  out = xb;  base = bid; }
    else if (bid < NXB + NWQB)  { in = wq; out = wqb; base = bid - NXB; }
    else                        { in = wp; out = wpb; base = bid - NXB - NWQB; }
    int i = (base * 256 + threadIdx.x) * 8;
    float4 a = *(const float4*)&in[i];
    float4 b = *(const float4*)&in[i + 4];
    bf16x8 o;
    o[0] = f2bf(a.x); o[1] = f2bf(a.y); o[2] = f2bf(a.z); o[3] = f2bf(a.w);
    o[4] = f2bf(b.x); o[5] = f2bf(b.y); o[6] = f2bf(b.z); o[7] = f2bf(b.w);
    *(bf16x8*)&out[i] = o;
}

// ---------------------------------------------------------------------------
// async global->LDS, 16B per lane
// ---------------------------------------------------------------------------
__device__ __forceinline__ void gload16(const void* g, void* l) {
    __builtin_amdgcn_global_load_lds(
        (const __attribute__((address_space(1))) unsigned*)g,
        (__attribute__((address_space(3))) unsigned*)l, 16, 0, 0);
}

#define BAR() do { __builtin_amdgcn_s_barrier(); \
                   __builtin_amdgcn_sched_barrier(0); } while (0)
#define VWAIT8() asm volatile("s_waitcnt vmcnt(8)" ::: "memory")
#define VWAIT0() asm volatile("s_waitcnt vmcnt(0)" ::: "memory")

// ---------------------------------------------------------------------------
// Kernel 1: qkv GEMM, 128x128 tile, BK=64, 4 waves (2M x 2N).
//
// Tile downsize from 256^2 (round 8): the guide's tile table shows 128^2 >
// 256^2 at the simple 2-barrier structure (912 vs 792 TF), and the 256^2
// grid (192 blocks) left 64 CUs idle. 768 blocks = 3/CU, 2 resident
// (64 KB static LDS dbuf) -> inter-block overlap hides barrier drains.
//
// Memory discipline IDENTICAL to the race-free round-5 schedule: all 8
// next-tile panel gloads issued at tile top, vmcnt(8) retires exactly the
// current tile's 8 while the next 8 stay in flight; 2 barriers/tile.
// B fragments loaded once per tile (8 ds_read_b128), A per i-row (2 reads,
// 8 MFMAs each).
//
// Bank swizzle: LDS[r][g^(r&7)] = G[r][g] on 16B granules, applied on the
// global source (gload_lds dest stays linear) and on the ds_read address.
// ---------------------------------------------------------------------------
__device__ __forceinline__ void stage_panel128(const short* __restrict__ src,
                                               int row0, int k0,
                                               short* dst, int tid)
{
#pragma unroll
    for (int u = 0; u < 4; ++u) {
        const int gidx = u * 256 + tid;        // 16B granule index (0..1023)
        const int rl   = gidx >> 3;            // row in panel (0..127)
        const int cc   = gidx & 7;             // 16B col granule (0..7)
        gload16(&src[(size_t)(row0 + rl) * 1024 + k0 + ((cc ^ (rl & 7)) << 3)],
                &dst[(size_t)gidx << 3]);      // linear LDS dest
    }
}

__device__ __forceinline__ void tile_compute(
    const short* Ac, const short* Bc, int wm, int wn,
    int lid, int quad, f32x4 (&acc)[4][4])
{
    bf16x8 bfr[4][2];
#pragma unroll
    for (int j2 = 0; j2 < 4; ++j2) {
        const int rb = wn + j2 * 16 + lid;
#pragma unroll
        for (int kk = 0; kk < 2; ++kk)
            bfr[j2][kk] = *(const bf16x8*)
                &Bc[rb * 64 + (((kk * 4 + quad) ^ (rb & 7)) << 3)];
    }
#pragma unroll
    for (int i2 = 0; i2 < 4; ++i2) {
        const int r = wm + i2 * 16 + lid;
        bf16x8 a0 = *(const bf16x8*)&Ac[r * 64 + (((quad) ^ (r & 7)) << 3)];
        bf16x8 a1 = *(const bf16x8*)&Ac[r * 64 + (((4 + quad) ^ (r & 7)) << 3)];
        __builtin_amdgcn_s_setprio(1);
#pragma unroll
        for (int j2 = 0; j2 < 4; ++j2) {
            acc[i2][j2] = __builtin_amdgcn_mfma_f32_16x16x32_bf16(
                a0, bfr[j2][0], acc[i2][j2], 0, 0, 0);
            acc[i2][j2] = __builtin_amdgcn_mfma_f32_16x16x32_bf16(
                a1, bfr[j2][1], acc[i2][j2], 0, 0, 0);
        }
        __builtin_amdgcn_s_setprio(0);
    }
}

__global__ __launch_bounds__(256, 2) void qkv_mfma(
    const short* __restrict__ xb,    // [4096][1024] bf16
    const short* __restrict__ wb,    // [3072][1024] bf16
    const float* __restrict__ bias,  // [3072] fp32
    short* __restrict__ qkvb)        // Q|Kf|Vf bf16
{
    __shared__ __attribute__((aligned(16))) short lds[2 * 16384];  // 64 KiB

    const int tid = threadIdx.x;
    // bijective XCD-chunked swizzle: nwg=768, 768%8==0, chunk=96
    const int T  = (blockIdx.x & 7) * 96 + (blockIdx.x >> 3);
    const int m0 = (T / 24) * 128;
    const int j0 = (T % 24) * 128;

    const int lane = tid & 63;
    const int w    = tid >> 6;
    const int quad = lane >> 4;
    const int lid  = lane & 15;
    const int wm = (w >> 1) * 64, wn = (w & 1) * 64;

    f32x4 acc[4][4];
#pragma unroll
    for (int i = 0; i < 4; ++i)
#pragma unroll
        for (int j = 0; j < 4; ++j) acc[i][j] = (f32x4){0.f, 0.f, 0.f, 0.f};

    // prologue: stage K-tile 0 into buf0 (A then B, 4+4 gloads/thread)
    stage_panel128(xb, m0, 0, lds,        tid);
    stage_panel128(wb, j0, 0, lds + 8192, tid);

#pragma unroll 2
    for (int kt = 0; kt < 15; ++kt) {
        const int cb = (kt & 1) << 14;
        const int nb = (~kt & 1) << 14;
        const int k1 = (kt + 1) << 6;
        const short* Ac = lds + cb;
        const short* Bc = Ac + 8192;

        // issue ALL next-tile panel loads up front (8 per thread)
        stage_panel128(xb, m0, k1, lds + nb,        tid);
        stage_panel128(wb, j0, k1, lds + nb + 8192, tid);

        // retire current tile's 8 loads; keep next tile's 8 in flight
        VWAIT8(); BAR();
        tile_compute(Ac, Bc, wm, wn, lid, quad, acc);
        BAR();                       // all waves done reading cb before it is
                                     // overwritten by next iteration's stage
    }
    // peeled last K-tile (kt=15, buf1, nothing left to stage)
    {
        const short* Ac = lds + 16384;
        VWAIT0(); BAR();
        tile_compute(Ac, Ac + 8192, wm, wn, lid, quad, acc);
    }

    // ---- epilogue (128^2 indexing, verified in round 0) ----
    const int s = j0 >> 10;            // uniform: 0:q 1:k 2:v

    if (s == 0) {
#pragma unroll
        for (int jb = 0; jb < 4; ++jb) {
            const int jj = j0 + wn + jb * 16 + lid;
            const int hh = (jj & 1023) >> 6;
            const int dd = jj & 63;
            const float bv = bias[jj];
#pragma unroll
            for (int i = 0; i < 4; ++i)
#pragma unroll
                for (int r = 0; r < 4; ++r) {
                    const int mrow = m0 + wm + i * 16 + quad * 4 + r;
                    const int b_ = mrow >> 11, nn = mrow & 2047;
                    qkvb[((size_t)(b_ * NHEADS + hh) * SEQ + nn) * HDIM + dd] =
                        f2bf((acc[i][jb][r] + bv) * QSCALE);
                }
        }
    } else if (s == 1) {
        // K: permuted fragment-major.
#pragma unroll
        for (int jb = 0; jb < 4; ++jb) {
            const int jj = j0 + wn + jb * 16 + lid;
            const int hh = (jj & 1023) >> 6;
            const int dd = jj & 63;
            const int c2 = dd >> 5;
            const int qd = (dd >> 3) & 3;
            const int jo = dd & 7;
            const float bv = bias[jj];
#pragma unroll
            for (int i = 0; i < 4; ++i) {
                const int mrow0 = m0 + wm + i * 16;
                const int b_ = mrow0 >> 11;
                const int n0 = mrow0 & 2047;
                const int t32 = n0 >> 5;
                const int i16 = (n0 >> 4) & 1;
                const int c = quad & 1;
                const int lidb = (i16 * 2 + (quad >> 1)) * 4;
                size_t base = QKVSZ + (size_t)(b_ * NHEADS + hh) * HEADEL +
                              (size_t)(t32 * 4 + c2 * 2 + c) * 512 +
                              (qd * 16 + lidb) * 8 + jo;
#pragma unroll
                for (int r = 0; r < 4; ++r)
                    qkvb[base + r * 8] = f2bf(acc[i][jb][r] + bv);
            }
        }
    } else {
        // V: x32-A fragment-major.
#pragma unroll
        for (int jb = 0; jb < 4; ++jb) {
            const int jj = j0 + wn + jb * 16 + lid;
            const int hh = (jj & 1023) >> 6;
            const int dd = jj & 63;
            const int fb = dd >> 4;
            const int dl = dd & 15;
            const float bv = bias[jj];
#pragma unroll
            for (int i = 0; i < 4; ++i) {
                const int mrow0 = m0 + wm + i * 16 + quad * 4;
                const int b_ = mrow0 >> 11, n0 = mrow0 & 2047;
                const int t32 = n0 >> 5;
                const int i16 = (n0 >> 4) & 1;
                const int quadpp = i16 * 2 + (quad >> 1);
                bf16x4 o;
#pragma unroll
                for (int r = 0; r < 4; ++r) o[r] = f2bf(acc[i][jb][r] + bv);
                *(bf16x4*)&qkvb[2 * QKVSZ + (size_t)(b_ * NHEADS + hh) * HEADEL +
                                (size_t)(t32 * 4 + fb) * 512 +
                                (quadpp * 16 + dl) * 8 + (quad & 1) * 4] = o;
            }
        }
    }
}

// ---------------------------------------------------------------------------
// Kernel 2: MFMA flash attention, zero in-loop sync, key-split-4, all-x32.
// XCD-aware block mapping; cvt_pk P-pack; setprio; single-buffer combine.
// THIS ROUND: 2-deep ping-pong K/V register prefetch (T14, +17% measured on
// attn): chunk cc+1's 8 loads issued BEFORE chunk cc's compute, so ~200cyc
// L2 latency hides under the ~500cyc compute phase. Two named frag sets
// (static indexing). VGPR ~88+32=120, stays <=128 (round-7 lesson: never
// clamp below live state).
// ---------------------------------------------------------------------------
__device__ __forceinline__ void load_kv(
    const short* __restrict__ Kf, const short* __restrict__ Vf,
    int t, int lane, bf16x8 (&aK)[2][2], bf16x8 (&aV)[4])
{
#pragma unroll
    for (int c = 0; c < 2; ++c)
#pragma unroll
        for (int c2 = 0; c2 < 2; ++c2)
            aK[c][c2] = *(const bf16x8*)&Kf[(size_t)(t * 4 + c2 * 2 + c) * 512 +
                                            lane * 8];
#pragma unroll
    for (int fb = 0; fb < 4; ++fb)
        aV[fb] = *(const bf16x8*)&Vf[(size_t)(t * 4 + fb) * 512 + lane * 8];
}

__device__ __forceinline__ void attn_chunk(
    const bf16x8 (&aK)[2][2], const bf16x8 (&aV)[4],
    const bf16x8 (&bQ)[4][2], const bf16x8& ones8,
    f32x4 (&O)[4][4], f32x4 (&L)[4])
{
#pragma unroll
    for (int g = 0; g < 4; ++g) {
        f32x4 s0 = (f32x4){0.f, 0.f, 0.f, 0.f};
        f32x4 s1 = (f32x4){0.f, 0.f, 0.f, 0.f};
        __builtin_amdgcn_s_setprio(1);
        s0 = __builtin_amdgcn_mfma_f32_16x16x32_bf16(aK[0][0], bQ[g][0], s0, 0, 0, 0);
        s1 = __builtin_amdgcn_mfma_f32_16x16x32_bf16(aK[1][0], bQ[g][0], s1, 0, 0, 0);
        s0 = __builtin_amdgcn_mfma_f32_16x16x32_bf16(aK[0][1], bQ[g][1], s0, 0, 0, 0);
        s1 = __builtin_amdgcn_mfma_f32_16x16x32_bf16(aK[1][1], bQ[g][1], s1, 0, 0, 0);
        __builtin_amdgcn_s_setprio(0);
        // P[j=quad*8+0..3] from tile0, P[j=+4..7] from tile1
        union { unsigned u[4]; bf16x8 v; } P;
        P.u[0] = cvt_pk_bf16(EXP2F(s0[0]), EXP2F(s0[1]));
        P.u[1] = cvt_pk_bf16(EXP2F(s0[2]), EXP2F(s0[3]));
        P.u[2] = cvt_pk_bf16(EXP2F(s1[0]), EXP2F(s1[1]));
        P.u[3] = cvt_pk_bf16(EXP2F(s1[2]), EXP2F(s1[3]));
        __builtin_amdgcn_s_setprio(1);
        L[g] = __builtin_amdgcn_mfma_f32_16x16x32_bf16(ones8, P.v, L[g], 0, 0, 0);
#pragma unroll
        for (int fb = 0; fb < 4; ++fb)
            O[g][fb] = __builtin_amdgcn_mfma_f32_16x16x32_bf16(
                aV[fb], P.v, O[g][fb], 0, 0, 0);
        __builtin_amdgcn_s_setprio(0);
    }
}

__global__ __launch_bounds__(256, 2) void attn_mfma(
    const short* __restrict__ qkvb,  // Q(pre-scaled)|Kf|Vf bf16
    short* __restrict__ aob)         // [B,N,C] bf16
{
    __shared__ float Osm[4][4][4][64];     // [g][fb][r][lane] = 16 KB
    __shared__ float Lsm[3][64];

    const int tid  = threadIdx.x;
    const int sp   = tid >> 6;        // key-split quarter
    const int lane = tid & 63;
    const int quad = lane >> 4;
    const int lid  = lane & 15;

    const int bid  = blockIdx.x;              // 0..1023
    const int xcd  = bid & 7;
    const int slot = bid >> 3;                // 0..127
    const int pair = xcd * 4 + (slot >> 5);   // 0..31
    const int qblk = slot & 31;
    const int h = pair & 15;
    const int b = pair >> 4;
    const int qbase = qblk * 64;

    const short* Qh = qkvb + (size_t)(b * NHEADS + h) * HEADEL;
    const short* Kf = Qh + QKVSZ;
    const short* Vf = qkvb + 2 * QKVSZ + (size_t)(b * NHEADS + h) * HEADEL;

    bf16x8 bQ[4][2];
#pragma unroll
    for (int g = 0; g < 4; ++g)
#pragma unroll
        for (int c = 0; c < 2; ++c)
            bQ[g][c] = *(const bf16x8*)&Qh[(size_t)(qbase + g * 16 + lid) * HDIM +
                                           c * 32 + quad * 8];

    f32x4 O[4][4];                    // [g][fb] O^T accum: row=d, col=q
    f32x4 L[4];                       // [g] row-sum accum (all rows equal)
#pragma unroll
    for (int g = 0; g < 4; ++g) {
        L[g] = (f32x4){0.f, 0.f, 0.f, 0.f};
#pragma unroll
        for (int fb = 0; fb < 4; ++fb) O[g][fb] = (f32x4){0.f, 0.f, 0.f, 0.f};
    }
    const bf16x8 ones8 = {(short)0x3F80, (short)0x3F80, (short)0x3F80, (short)0x3F80,
                          (short)0x3F80, (short)0x3F80, (short)0x3F80, (short)0x3F80};

    // 2-deep ping-pong: set0 holds even chunks, set1 odd chunks.
    bf16x8 aK0[2][2], aV0[4], aK1[2][2], aV1[4];
    const int t0 = sp * (SEQ / 128);          // 16 chunks per split
    load_kv(Kf, Vf, t0, lane, aK0, aV0);
#pragma unroll 2
    for (int cc = 0; cc < 16; cc += 2) {
        load_kv(Kf, Vf, t0 + cc + 1, lane, aK1, aV1);       // prefetch odd
        attn_chunk(aK0, aV0, bQ, ones8, O, L);              // compute even
        if (cc + 2 < 16)
            load_kv(Kf, Vf, t0 + cc + 2, lane, aK0, aV0);   // prefetch even
        attn_chunk(aK1, aV1, bQ, ones8, O, L);              // compute odd
    }

    // ---- split-4 combine, single 16 KB buffer, 5 barrier steps ----
    if (sp != 0 && quad == 0)
#pragma unroll
        for (int g = 0; g < 4; ++g) Lsm[sp - 1][g * 16 + lid] = L[g][0];

    if (sp == 1) {                    // step 1: sp1 publish
#pragma unroll
        for (int g = 0; g < 4; ++g)
#pragma unroll
            for (int fb = 0; fb < 4; ++fb)
#pragma unroll
                for (int r = 0; r < 4; ++r)
                    Osm[g][fb][r][lane] = O[g][fb][r];
    }
    __syncthreads();
    if (sp == 0) {                    // step 2: sp0 += sp1
#pragma unroll
        for (int g = 0; g < 4; ++g)
#pragma unroll
            for (int fb = 0; fb < 4; ++fb)
#pragma unroll
                for (int r = 0; r < 4; ++r)
                    O[g][fb][r] += Osm[g][fb][r][lane];
    }
    __syncthreads();
    if (sp == 3) {                    // step 3: sp3 publish
#pragma unroll
        for (int g = 0; g < 4; ++g)
#pragma unroll
            for (int fb = 0; fb < 4; ++fb)
#pragma unroll
                for (int r = 0; r < 4; ++r)
                    Osm[g][fb][r][lane] = O[g][fb][r];
    }
    __syncthreads();
    if (sp == 2) {                    // step 4: sp2 += sp3
#pragma unroll
        for (int g = 0; g < 4; ++g)
#pragma unroll
            for (int fb = 0; fb < 4; ++fb)
#pragma unroll
                for (int r = 0; r < 4; ++r)
                    O[g][fb][r] += Osm[g][fb][r][lane];
    }
    __syncthreads();
    if (sp == 2) {                    // step 5: sp2 publish (sp2+sp3)
#pragma unroll
        for (int g = 0; g < 4; ++g)
#pragma unroll
            for (int fb = 0; fb < 4; ++fb)
#pragma unroll
                for (int r = 0; r < 4; ++r)
                    Osm[g][fb][r][lane] = O[g][fb][r];
    }
    __syncthreads();
    if (sp == 0) {                    // final: sp0 has sp0+sp1; add (sp2+sp3)
#pragma unroll
        for (int g = 0; g < 4; ++g) {
            const float lt = L[g][0] + Lsm[0][g * 16 + lid] +
                             Lsm[1][g * 16 + lid] + Lsm[2][g * 16 + lid];
            const float inv = 1.f / lt;
            const int n = qbase + g * 16 + lid;
            size_t base = ((size_t)(b * SEQ + n)) * DIMC + h * HDIM;
#pragma unroll
            for (int fb = 0; fb < 4; ++fb) {
                bf16x4 o;
#pragma unroll
                for (int r = 0; r < 4; ++r)
                    o[r] = f2bf((O[g][fb][r] + Osm[g][fb][r][lane]) * inv);
                *(bf16x4*)&aob[base + fb * 16 + quad * 4] = o;
            }
        }
    }
}

// ---------------------------------------------------------------------------
// Kernel 3: out = ao_bf @ w_proj_bf^T + b_proj (MFMA, BK=64), fp32 out.
// ---------------------------------------------------------------------------
__global__ __launch_bounds__(256, 2) void proj_mfma(
    const short* __restrict__ ab,    // [4096][1024] bf16
    const short* __restrict__ wb,    // [1024][1024] bf16
    const float* __restrict__ bias,  // [1024] fp32
    float* __restrict__ out)         // [4096][1024] fp32
{
    __shared__ __attribute__((aligned(16))) short Asm[2 * 64 * 32];
    __shared__ __attribute__((aligned(16))) short Bsm[2 * 128 * 32];

    const int tid = threadIdx.x;
    const int m0 = blockIdx.y * 64;
    const int j0 = blockIdx.x * 128;

    const int lane = tid & 63;
    const int w    = tid >> 6;
    const int quad = lane >> 4;
    const int lid  = lane & 15;
    const int wm = (w >> 1) * 32, wn = (w & 1) * 64;

    const int srow = lane >> 2;
    const int skc  = (lane & 3) * 8;

    f32x4 acc[2][4];
#pragma unroll
    for (int i = 0; i < 2; ++i)
#pragma unroll
        for (int j = 0; j < 4; ++j) acc[i][j] = (f32x4){0.f, 0.f, 0.f, 0.f};

    for (int k0 = 0; k0 < 1024; k0 += 64) {
        __syncthreads();
#pragma unroll
        for (int u = 0; u < 2; ++u) {
            const int combo = w * 2 + u;        // 0..7
            const int hh = combo >> 2, rb = combo & 3;
            const int row = rb * 16 + srow;
            gload16(&ab[(size_t)(m0 + row) * 1024 + k0 + hh * 32 + skc],
                    &Asm[hh * 2048 + row * 32 + skc]);
        }
#pragma unroll
        for (int u = 0; u < 4; ++u) {
            const int combo = w * 4 + u;        // 0..15
            const int hh = combo >> 3, rb = combo & 7;
            const int row = rb * 16 + srow;
            gload16(&wb[(size_t)(j0 + row) * 1024 + k0 + hh * 32 + skc],
                    &Bsm[hh * 4096 + row * 32 + skc]);
        }
        __syncthreads();

#pragma unroll
        for (int hh = 0; hh < 2; ++hh) {
            bf16x8 af[2], bfr[4];
#pragma unroll
            for (int i = 0; i < 2; ++i)
                af[i] = *(const bf16x8*)&Asm[hh * 2048 + (wm + i * 16 + lid) * 32 + quad * 8];
#pragma unroll
            for (int j = 0; j < 4; ++j)
                bfr[j] = *(const bf16x8*)&Bsm[hh * 4096 + (wn + j * 16 + lid) * 32 + quad * 8];
#pragma unroll
            for (int i = 0; i < 2; ++i)
#pragma unroll
                for (int j = 0; j < 4; ++j)
                    acc[i][j] = __builtin_amdgcn_mfma_f32_16x16x32_bf16(
                        af[i], bfr[j], acc[i][j], 0, 0, 0);
        }
    }

#pragma unroll
    for (int jb = 0; jb < 4; ++jb) {
        const int jj = j0 + wn + jb * 16 + lid;
        const float bv = bias[jj];
#pragma unroll
        for (int i = 0; i < 2; ++i)
#pragma unroll
            for (int r = 0; r < 4; ++r) {
                const int mrow = m0 + wm + i * 16 + quad * 4 + r;
                out[(size_t)mrow * DIMC + jj] = acc[i][jb][r] + bv;
            }
    }
}

// ---------------------------------------------------------------------------
extern "C" void kernel_launch(void* const* d_in, const int* in_sizes, int n_in,
                              void* d_out, int out_size, void* d_ws, size_t ws_size,
                              hipStream_t stream) {
    const float* x      = (const float*)d_in[0];
    const float* w_qkv  = (const float*)d_in[1];
    const float* b_qkv  = (const float*)d_in[2];
    const float* w_proj = (const float*)d_in[3];
    const float* b_proj = (const float*)d_in[4];
    float* out = (float*)d_out;

    short* qkvb   = (short*)d_ws;                  // Q|Kf|Vf: 3*QKVSZ
    short* xb     = qkvb + 3 * QKVSZ;
    short* wqkvb  = xb + (size_t)MTOT * DIMC;
    short* wprojb = wqkvb + (size_t)QKVN * DIMC;
    short* aob    = wprojb + (size_t)DIMC * DIMC;

    cast_all<<<NXB + NWQB + NWPB, 256, 0, stream>>>(x, w_qkv, w_proj,
                                                    xb, wqkvb, wprojb);

    qkv_mfma<<<768, 256, 0, stream>>>(xb, wqkvb, b_qkv, qkvb);

    attn_mfma<<<BATCH * NHEADS * (SEQ / 64), 256, 0, stream>>>(qkvb, aob);

    dim3 g3(DIMC / 128, MTOT / 64);                // 8 x 64 = 512
    proj_mfma<<<g3, 256, 0, stream>>>(aob, wprojb, b_proj, out);
}